// Round 15
// baseline (543.633 us; speedup 1.0000x reference)
//
#include <hip/hip_runtime.h>
#include <stdint.h>

// ===========================================================================
// ROUND 15 — FULL SAMPLER, RESTRUCTURED TO DODGE THE BUILD POISON. LAUNCHED.
//
// Ledger: hang is build-side only (R10/R13 vs R14 prove no pod wedge).
// Clean: straight-line math incl f64 (R11), threefry unroll-1 64-loop (R14A),
// LDS+syncthreads straight-line (R14B), loads/branches/stores (R9/R11).
// Poison: some interaction inside the loop body {f32 cmp-select argmax,
// LDS-read-in-loop, u-branch} (R13 hung without logs; R14 parts clean).
//
// This build avoids the two prime suspects at once:
//   - NO LDS anywhere: logits precomputed to d_ws by a 64-thread
//     straight-line kernel (R11-proven class); main loop reads them from
//     global (L1 broadcast).
//   - BRANCHLESS argmax: monotone f32->u32 map, key=(mono(v)<<32)|(63-e),
//     u64 max. Ties -> smaller e == jnp.argmax first-wins.
// PRNG chain unchanged (partitionable threefry, verified 4x):
//   key=(0,42); k_sel=TF(key,(0,0)); k_samp=TF(key,(0,1))
//   sel = (o0^o1 of TF(split(k_sel)[1],(0,0))) % 32
//   bits(t,e) = o0^o1 of TF(k_samp,(0,t*64+e)); f=bitcast((bits>>9)|1.0f)-1
//   u = f==0 ? FLT_MIN : f;  g=-log(-log(u)) (f32-rounded); argmax(g+log p).
// ===========================================================================

#define EROT(a, b, r)                            \
  do {                                           \
    a += b;                                      \
    b = (b << (r)) | (b >> (32 - (r)));          \
    b ^= a;                                      \
  } while (0)

#define ETF_BODY(k0, k1, x0, x1)                                      \
  {                                                                   \
    uint32_t kx = (k0) ^ (k1) ^ 0x1BD11BDAu;                          \
    x0 += (k0); x1 += (k1);                                           \
    EROT(x0, x1, 13); EROT(x0, x1, 15); EROT(x0, x1, 26); EROT(x0, x1, 6); \
    x0 += (k1); x1 += kx + 1u;                                        \
    EROT(x0, x1, 17); EROT(x0, x1, 29); EROT(x0, x1, 16); EROT(x0, x1, 24); \
    x0 += kx; x1 += (k0) + 2u;                                        \
    EROT(x0, x1, 13); EROT(x0, x1, 15); EROT(x0, x1, 26); EROT(x0, x1, 6); \
    x0 += (k0); x1 += (k1) + 3u;                                      \
    EROT(x0, x1, 17); EROT(x0, x1, 29); EROT(x0, x1, 16); EROT(x0, x1, 24); \
    x0 += (k1); x1 += kx + 4u;                                        \
    EROT(x0, x1, 13); EROT(x0, x1, 15); EROT(x0, x1, 26); EROT(x0, x1, 6); \
    x0 += kx; x1 += (k0) + 5u;                                        \
  }

// ------------------- double-float (2x f32) arithmetic ----------------------
struct edf { float hi, lo; };
__device__ inline edf e_two_sum(float a, float b) {
  float s = a + b, bb = s - a;
  return {s, (a - (s - bb)) + (b - bb)};
}
__device__ inline edf e_fast2(float a, float b) {
  float s = a + b;
  return {s, b - (s - a)};
}
__device__ inline edf e_prod(float a, float b) {
  float p = a * b;
  return {p, fmaf(a, b, -p)};
}
__device__ inline edf e_add(edf a, edf b) {
  edf s = e_two_sum(a.hi, b.hi);
  return e_fast2(s.hi, s.lo + a.lo + b.lo);
}
__device__ inline edf e_mul(edf a, edf b) {
  edf p = e_prod(a.hi, b.hi);
  return e_fast2(p.hi, p.lo + fmaf(a.hi, b.lo, a.lo * b.hi));
}
__device__ inline edf e_div(edf a, edf b) {
  float q1 = a.hi / b.hi;
  edf p = e_prod(q1, b.hi);
  float r = ((a.hi - p.hi) + a.lo) - (p.lo + q1 * b.lo);
  return e_fast2(q1, r / b.hi);
}

// f32 log, ~1e-11 rel err (double-float): x = 2^e*m, m in [sqrt2/2,sqrt2),
// log(m) = 2*atanh(s), s = (m-1)/(m+1) (m-1 exact by Sterbenz).
__device__ inline float edflogf(float x) {
  uint32_t b = __float_as_uint(x);
  int e = (int)(b >> 23) - 127;
  float m = __uint_as_float((b & 0x007FFFFFu) | 0x3F800000u);
  if (m > 1.41421356f) { m *= 0.5f; e += 1; }
  float num = m - 1.0f;
  edf den = e_two_sum(m, 1.0f);
  edf s = e_div({num, 0.0f}, den);
  edf t = e_mul(s, s);
  float tf = t.hi;
  float T = 1.0f / 15.0f;
  T = fmaf(T, tf, 1.0f / 13.0f);
  T = fmaf(T, tf, 1.0f / 11.0f);
  T = fmaf(T, tf, 1.0f / 9.0f);
  T = fmaf(T, tf, 1.0f / 7.0f);
  T = fmaf(T, tf, 1.0f / 5.0f);
  const edf third = {0.33333334f, -9.934107e-9f};
  edf P = e_mul(t, third);
  P = e_add(P, e_mul(e_mul(t, t), {T, 0.0f}));
  edf S = e_add({1.0f, 0.0f}, P);
  edf logm = e_mul(s, S);
  logm.hi *= 2.0f; logm.lo *= 2.0f;
  const edf ln2 = {0.6931472f, -1.9046542e-9f};
  edf res = e_add(e_mul({(float)e, 0.0f}, ln2), logm);
  return res.hi;
}

// Straight-line logit kernel (R11-proven class): 64 threads, one block.
__global__ __launch_bounds__(64) void elogit_kernel(
    const float* __restrict__ prob_row, float* __restrict__ logits_ws) {
  const int i = threadIdx.x;  // 0..63
  logits_ws[i] = edflogf(prob_row[i]);
}

// Main sampler: no LDS, branchless u64-max argmax, logits from global.
__global__ __launch_bounds__(256) void egate_sample(
    const float* __restrict__ logits_g, float* __restrict__ out,
    uint32_t s0, uint32_t s1, int n_tokens) {
  const int t = blockIdx.x * blockDim.x + threadIdx.x;
  if (t >= n_tokens) return;

  const uint32_t cbase = (uint32_t)t << 6;
  unsigned long long bk = 0ULL;  // mono(v) > 0 always => 0 is minus-infinity

#pragma unroll 1
  for (int e = 0; e < 64; ++e) {
    uint32_t x0 = 0u, x1 = cbase + (uint32_t)e;
    ETF_BODY(s0, s1, x0, x1);
    const uint32_t bits = x0 ^ x1;
    float u = __uint_as_float((bits >> 9) | 0x3f800000u) - 1.0f;
    u = (u == 0.0f) ? 1.17549435e-38f : u;  // minval = FLT_MIN (select)
    const float lg1 = edflogf(u);
    const float lg2 = edflogf(-lg1);
    const float v = (-lg2) + logits_g[e];
    const uint32_t vb = __float_as_uint(v);
    const uint32_t mono = (vb & 0x80000000u) ? ~vb : (vb | 0x80000000u);
    const unsigned long long key =
        ((unsigned long long)mono << 32) | (unsigned long long)(63 - e);
    bk = (key > bk) ? key : bk;  // ties in v -> larger 63-e -> smaller e
  }
  out[t] = (float)(63 - (int)(bk & 63ULL));
}

// ------------------------------- host side ---------------------------------
static void etf_host(uint32_t k0, uint32_t k1, uint32_t x0, uint32_t x1,
                     uint32_t* o0, uint32_t* o1) {
  ETF_BODY(k0, k1, x0, x1);
  *o0 = x0;
  *o1 = x1;
}

extern "C" void kernel_launch(void* const* d_in, const int* in_sizes, int n_in,
                              void* d_out, int out_size, void* d_ws, size_t ws_size,
                              hipStream_t stream) {
  const float* prob_board = (const float*)d_in[1];
  float* out = (float*)d_out;
  float* logits_ws = (float*)d_ws;  // 64 floats

  const int n_tokens = in_sizes[0] / 128;  // d_model=128 -> 1048576
  const int n_experts = 64;

  uint32_t a0, a1, b0, b1, c0, c1, r0, r1;
  etf_host(0u, 42u, 0u, 0u, &a0, &a1);  // k_sel
  etf_host(0u, 42u, 0u, 1u, &b0, &b1);  // k_samp
  etf_host(a0, a1, 0u, 1u, &c0, &c1);   // kB = split(k_sel)[1]
  etf_host(c0, c1, 0u, 0u, &r0, &r1);   // random_bits(kB, 32, ())
  const uint32_t sel = (r0 ^ r1) & 31u;

  const float* prob_row = prob_board + (size_t)sel * n_experts;

  elogit_kernel<<<1, 64, 0, stream>>>(prob_row, logits_ws);
  const int block = 256;
  const int grid = (n_tokens + block - 1) / block;
  egate_sample<<<grid, block, 0, stream>>>(logits_ws, out, b0, b1, n_tokens);
}